// Round 1
// 104.423 us; speedup vs baseline: 1.0405x; 1.0405x over previous
//
#include <hip/hip_runtime.h>

#define BB 8
#define CC 64
#define NNN 4096
#define KK 20
#define MM 8
#define OC 64
#define CM 512

typedef __attribute__((ext_vector_type(8))) short bf16x8;
typedef __attribute__((ext_vector_type(4))) float f32x4;

__device__ __forceinline__ unsigned short f2bf(float f) {
    union { float f; unsigned int u; } v; v.f = f;
    unsigned int u = v.u;
    return (unsigned short)((u + 0x7FFFu + ((u >> 16) & 1u)) >> 16);
}
__device__ __forceinline__ float bfhi2f(unsigned int u) {
    union { unsigned int u; float f; } v; v.u = u & 0xffff0000u; return v.f;
}
__device__ __forceinline__ float bflo2f(unsigned int u) {
    union { unsigned int u; float f; } v; v.u = u << 16; return v.f;
}

// v_dot2_f32_bf16: D = a.lo*b.lo + a.hi*b.hi + c  (bf16 products, f32 accum)
#if __has_builtin(__builtin_amdgcn_fdot2_f32_bf16)
typedef __attribute__((ext_vector_type(2))) __bf16 bf16x2_t;
__device__ __forceinline__ float dot2bf(unsigned int a, unsigned int b, float c) {
    union { unsigned int u; bf16x2_t v; } ua, ub; ua.u = a; ub.u = b;
    return __builtin_amdgcn_fdot2_f32_bf16(ua.v, ub.v, c, false);
}
#else
__device__ __forceinline__ float dot2bf(unsigned int a, unsigned int b, float c) {
    float d;
    asm("v_dot2_f32_bf16 %0, %1, %2, %3" : "=v"(d) : "v"(a), "v"(b), "v"(c));
    return d;
}
#endif

// Kernel 1: transpose feature (B,C,N)->(B,N,C) bf16 into ws; conv_w -> bf16 [o][k]
__global__ __launch_bounds__(256) void prep_kernel(const float* __restrict__ feature,
                                                   const float* __restrict__ conv_w,
                                                   unsigned short* __restrict__ ftr,
                                                   unsigned short* __restrict__ Wb) {
    int blk = blockIdx.x;
    int t = threadIdx.x;
    if (blk < 512) {
        __shared__ float tile[64 * 65];
        int b = blk & 7;
        int n0 = (blk >> 3) << 6;
        const float* fb = feature + b * (CC * NNN);
        #pragma unroll
        for (int s = 0; s < 16; ++s) {
            int i = t + s * 256;
            int c = i >> 6, nn = i & 63;
            tile[c * 65 + nn] = fb[c * NNN + n0 + nn];
        }
        __syncthreads();
        unsigned short* fo = ftr + b * (NNN * CC) + n0 * CC;
        #pragma unroll
        for (int s = 0; s < 16; ++s) {
            int i = t + s * 256;
            int n = i >> 6, cc = i & 63;
            fo[n * CC + cc] = f2bf(tile[cc * 65 + n]);
        }
    } else {
        int base = (blk - 512) * 8192;
        #pragma unroll
        for (int s = 0; s < 32; ++s) {
            int i = base + t + s * 256;
            Wb[i] = f2bf(conv_w[i]);
        }
    }
}

// Kernel 2: 16 points/block; prefetch-overlapped phases; LDS overlay.
// Phase B now uses v_dot2_f32_bf16 (2 bf16 MACs/inst) instead of scalar f32 FMA:
// perm is packed to bf16 k-pairs in phase A; f k-pairs built in-register via v_perm_b32.
__global__ __launch_bounds__(256, 4) void main_kernel(
    const float* __restrict__ x,
    const float* __restrict__ feature,
    const int* __restrict__ nidx,
    const float* __restrict__ kern,
    const float* __restrict__ conv_b,
    const unsigned short* __restrict__ ftr,
    const unsigned short* __restrict__ Wb,
    float* __restrict__ out)
{
    // overlay: early-phase buffers are dead by the time aggA is written
    __shared__ __align__(16) union {
        struct {
            int   idx[16 * KK];             // 1280 B
            float xn[16 * KK * 3];          // 3840 B
            unsigned int permb[16 * 10 * MM]; // 5120 B: [p][kpair][m] = bf16x2 {perm[2i],perm[2i+1]}
        } s;
        unsigned short aggA[16 * 520];      // 16640 B (pad 512->520)
    } u;

    int t = threadIdx.x;
    int blk = blockIdx.x;
    int b = blk & 7;                 // XCD-affinity swizzle
    int n0 = (blk >> 3) << 4;
    int w = t >> 6, l = t & 63;

    // ---- independent prefetches (issued before anything else) ----
    int o = (w << 4) + (l & 15);     // output channel for phase C / epilogue
    int pq = (l >> 4) << 2;          // point quad within the 16-point tile
    float4 fres4 = *(const float4*)(feature + ((size_t)b * CC + o) * NNN + n0 + pq);
    float bias = conv_b[o];
    int m_pre = t & 7;
    float kw0 = kern[m_pre], kw1 = kern[MM + m_pre], kw2 = kern[2 * MM + m_pre];

    // ---- stage neighbor indices ----
    const int* nb = nidx + (b * NNN + n0) * KK;
    for (int i = t; i < 16 * KK; i += 256) u.s.idx[i] = nb[i];
    __syncthreads();

    // ---- issue xyz gathers (regs), then ftr gathers (regs) ----
    const float* xb = x + b * (3 * NNN);
    float xreg[4];
    int xslot[4];
    #pragma unroll
    for (int s = 0; s < 4; ++s) {
        int i = t + s * 256;
        xslot[s] = i;
        if (i < 960) {
            int p2 = i / 60;
            int rem = i - p2 * 60;
            int k = rem / 3;
            int c = rem - k * 3;
            xreg[s] = xb[c * NNN + u.s.idx[p2 * KK + k]];
        }
    }

    int p = t >> 4;                  // point for phase B
    int cq = (t & 15) << 2;          // 4 channels for phase B
    const unsigned short* fb = ftr + (size_t)b * (NNN * CC);
    uint2 fr[KK];
    #pragma unroll
    for (int k = 0; k < KK; ++k)
        fr[k] = *(const uint2*)(fb + (size_t)u.s.idx[p * KK + k] * CC + cq);

    // commit xyz to LDS (waits only on the xyz loads; ftr stays in flight)
    #pragma unroll
    for (int s = 0; s < 4; ++s)
        if (xslot[s] < 960) u.s.xn[xslot[s]] = xreg[s];
    __syncthreads();

    // ---- phase A: permatrix + softmax over k (thread = (point, m)); pack bf16 k-pairs ----
    if (t < 128) {
        int pp = t >> 3;
        int m = t & 7;
        const float* xp = &u.s.xn[pp * 60];
        float bx = xp[0], by = xp[1], bz = xp[2];
        float pv[KK];
        #pragma unroll
        for (int k = 0; k < KK; ++k) {
            float dx = xp[k * 3 + 0] - bx;
            float dy = xp[k * 3 + 1] - by;
            float dz = xp[k * 3 + 2] - bz;
            pv[k] = dx * kw0 + dy * kw1 + dz * kw2;
        }
        if (m == 0) pv[0] += 1.0f;
        float mx = pv[0];
        #pragma unroll
        for (int k = 1; k < KK; ++k) mx = fmaxf(mx, pv[k]);
        float sum = 0.f;
        #pragma unroll
        for (int k = 0; k < KK; ++k) { pv[k] = __expf(pv[k] - mx); sum += pv[k]; }
        float inv = 1.0f / sum;
        #pragma unroll
        for (int i = 0; i < 10; ++i) {
            unsigned int lo = f2bf(pv[2 * i] * inv);
            unsigned int hi = f2bf(pv[2 * i + 1] * inv);
            u.s.permb[(pp * 10 + i) * MM + m] = lo | (hi << 16);
        }
    }
    __syncthreads();

    // ---- phase B: agg[p][c][m] += f[k][c]*perm[k][m] via v_dot2_f32_bf16 over k-pairs ----
    float acc[4][MM];
    #pragma unroll
    for (int ci = 0; ci < 4; ++ci)
        #pragma unroll
        for (int m = 0; m < MM; ++m) acc[ci][m] = 0.f;

    const unsigned int* pb = &u.s.permb[p * 10 * MM];
    #pragma unroll
    for (int i = 0; i < 10; ++i) {
        uint4 pm0 = *(const uint4*)(pb + i * MM);
        uint4 pm1 = *(const uint4*)(pb + i * MM + 4);
        // build f k-pairs: {f[2i][c], f[2i+1][c]} from c-packed gathers
        unsigned int fp0 = __builtin_amdgcn_perm(fr[2 * i + 1].x, fr[2 * i].x, 0x05040100u);
        unsigned int fp1 = __builtin_amdgcn_perm(fr[2 * i + 1].x, fr[2 * i].x, 0x07060302u);
        unsigned int fp2 = __builtin_amdgcn_perm(fr[2 * i + 1].y, fr[2 * i].y, 0x05040100u);
        unsigned int fp3 = __builtin_amdgcn_perm(fr[2 * i + 1].y, fr[2 * i].y, 0x07060302u);
        unsigned int fpv[4] = {fp0, fp1, fp2, fp3};
        unsigned int pmv[8] = {pm0.x, pm0.y, pm0.z, pm0.w, pm1.x, pm1.y, pm1.z, pm1.w};
        #pragma unroll
        for (int ci = 0; ci < 4; ++ci)
            #pragma unroll
            for (int m = 0; m < MM; ++m)
                acc[ci][m] = dot2bf(fpv[ci], pmv[m], acc[ci][m]);
    }
    __syncthreads();   // all permb reads done before aggA overlays it

    #pragma unroll
    for (int ci = 0; ci < 4; ++ci) {
        union { bf16x8 v; unsigned short s2[8]; } pk;
        #pragma unroll
        for (int m = 0; m < MM; ++m) pk.s2[m] = f2bf(acc[ci][m]);
        *(bf16x8*)&u.aggA[p * 520 + (cq + ci) * MM] = pk.v;
    }
    __syncthreads();

    // ---- phase C: (16 pts x 512) @ (512 x 16 o) per wave via MFMA + fused epilogue ----
    {
        int row = l & 15;
        int kg = (l >> 4) << 3;
        f32x4 acc2 = {0.f, 0.f, 0.f, 0.f};
        const unsigned short* wrow = Wb + (size_t)o * CM;
        const unsigned short* arow = u.aggA + row * 520;
        #pragma unroll
        for (int s = 0; s < 16; ++s) {
            int k = s * 32 + kg;
            bf16x8 af = *(const bf16x8*)&arow[k];
            bf16x8 bfr = *(const bf16x8*)&wrow[k];
            acc2 = __builtin_amdgcn_mfma_f32_16x16x32_bf16(af, bfr, acc2, 0, 0, 0);
        }
        float4 res;
        #pragma unroll
        for (int r = 0; r < 4; ++r) {
            float v = acc2[r] + bias;
            v = v > 0.f ? v : v * 0.2f;
            ((float*)&res)[r] = v + ((const float*)&fres4)[r];
        }
        *(float4*)(out + ((size_t)b * CC + o) * NNN + n0 + pq) = res;
    }
}

extern "C" void kernel_launch(void* const* d_in, const int* in_sizes, int n_in,
                              void* d_out, int out_size, void* d_ws, size_t ws_size,
                              hipStream_t stream) {
    const float* x        = (const float*)d_in[0];
    const float* feature  = (const float*)d_in[1];
    const int*   nidx     = (const int*)d_in[2];
    const float* kern     = (const float*)d_in[3];
    const float* conv_w   = (const float*)d_in[4];
    const float* conv_b   = (const float*)d_in[5];
    float* out = (float*)d_out;

    unsigned short* ftr = (unsigned short*)d_ws;                      // 4 MB: (B,N,C) bf16
    unsigned short* Wb  = (unsigned short*)((char*)d_ws + 4194304);   // 64 KB: bf16 W [o][k]

    prep_kernel<<<516, 256, 0, stream>>>(feature, conv_w, ftr, Wb);
    main_kernel<<<2048, 256, 0, stream>>>(x, feature, nidx, kern, conv_b, ftr, Wb, out);
}